// Round 4
// baseline (252.658 us; speedup 1.0000x reference)
//
#include <hip/hip_runtime.h>
#include <hip/hip_bf16.h>
#include <stdint.h>

#define S 4096
#define HID 1024
#define NH 16
#define DH 64

typedef __attribute__((ext_vector_type(8))) short short8;
typedef __attribute__((ext_vector_type(4))) float f32x4;
typedef __attribute__((ext_vector_type(16))) float f32x16;
typedef __attribute__((ext_vector_type(4))) unsigned int u32x4;

__device__ __forceinline__ unsigned short f2bf(float f) {
  unsigned int u = __builtin_bit_cast(unsigned int, f);
  u += 0x7FFF + ((u >> 16) & 1);   // round-to-nearest-even
  return (unsigned short)(u >> 16);
}
// pack two fp32 -> bf16x2 dword by truncation (1 v_perm_b32)
__device__ __forceinline__ unsigned int pktrunc(float lo, float hi) {
  return __builtin_amdgcn_perm(__builtin_bit_cast(unsigned int, hi),
                               __builtin_bit_cast(unsigned int, lo), 0x07060302u);
}
// async global->LDS, 16B per lane. LDS pointer MUST be wave-uniform;
// HW writes lane i at ldsbase + i*16B (m104/m108 semantics).
__device__ __forceinline__ void gload16(const unsigned short* g, unsigned short* l) {
  __builtin_amdgcn_global_load_lds((const __attribute__((address_space(1))) unsigned int*)g,
                                   (__attribute__((address_space(3))) unsigned int*)l, 16, 0, 0);
}

// ---------------------------------------------------------------- cast fp32 -> bf16
__global__ __launch_bounds__(256) void cast_kernel(
    const float* __restrict__ x,  const float* __restrict__ wq,
    const float* __restrict__ wk, const float* __restrict__ wv,
    const float* __restrict__ wo,
    unsigned short* __restrict__ xb,  unsigned short* __restrict__ wqb,
    unsigned short* __restrict__ wkb, unsigned short* __restrict__ wvb,
    unsigned short* __restrict__ wob)
{
  int y = blockIdx.y;
  const float* src; unsigned short* dst; int n;
  if      (y == 0) { src = x;  dst = xb;  n = S * HID; }
  else if (y == 1) { src = wq; dst = wqb; n = HID * HID; }
  else if (y == 2) { src = wk; dst = wkb; n = HID * HID; }
  else if (y == 3) { src = wv; dst = wvb; n = HID * HID; }
  else             { src = wo; dst = wob; n = HID * HID; }
  int i = (blockIdx.x * 256 + threadIdx.x) * 4;
  if (i < n) {
    float4 v = *reinterpret_cast<const float4*>(src + i);
    ushort4 o;
    o.x = f2bf(v.x); o.y = f2bf(v.y); o.z = f2bf(v.z); o.w = f2bf(v.w);
    *reinterpret_cast<ushort4*>(dst + i) = o;
  }
}

// ---------------------------------------------------------------- 128x128 NT GEMM core (m97-style)
__device__ __forceinline__ void gemm128(
    const unsigned short* __restrict__ A, const unsigned short* __restrict__ W,
    unsigned short* As, unsigned short* Bs, f32x4 acc[4][4], int row0, int col0)
{
  const int tid = threadIdx.x;
  const int wave = tid >> 6, lane = tid & 63, quad = lane >> 4, l16 = lane & 15;
  const int wr = (wave >> 1) * 64, wc = (wave & 1) * 64;
  const int srow = lane >> 2, sseg = lane & 3;
  const f32x4 z = {0.f, 0.f, 0.f, 0.f};
  #pragma unroll
  for (int i = 0; i < 4; i++)
    #pragma unroll
    for (int j = 0; j < 4; j++) acc[i][j] = z;

  for (int k0 = 0; k0 < HID; k0 += 32) {
    __syncthreads();
    #pragma unroll
    for (int c = 0; c < 2; c++) {
      const int rbase = c * 64 + wave * 16;
      gload16(A + (size_t)(row0 + rbase + srow) * HID + k0 + sseg * 8, As + rbase * 32);
      gload16(W + (size_t)(col0 + rbase + srow) * HID + k0 + sseg * 8, Bs + rbase * 32);
    }
    __syncthreads();

    short8 af[4], bfr[4];
    #pragma unroll
    for (int i = 0; i < 4; i++)
      af[i] = *reinterpret_cast<const short8*>(As + (wr + i * 16 + l16) * 32 + quad * 8);
    #pragma unroll
    for (int j = 0; j < 4; j++)
      bfr[j] = *reinterpret_cast<const short8*>(Bs + (wc + j * 16 + l16) * 32 + quad * 8);
    #pragma unroll
    for (int i = 0; i < 4; i++)
      #pragma unroll
      for (int j = 0; j < 4; j++)
        acc[i][j] = __builtin_amdgcn_mfma_f32_16x16x32_bf16(af[i], bfr[j], acc[i][j], 0, 0, 0);
  }
}

// QKV projections. Q -> [H][S][64] prescaled by log2e/8.
// K -> K2 frag-packed (K=16 A-op): K2[(((h*128+g)*4+c)*64 + lane)*8 + j]
// V -> Vb frag-packed (K=16 B-op with keys bitswap23-relabeled):
//      Vb[((((h*128+gt)*2+grp)*2+ng)*64 + hf*32 + l32)*8 + j]
//      holds V[key = gt*32+grp*16+bitswap23(hf*8+j)][d = ng*32+l32]
//      so that the S^T C-layout reg-octet IS a valid K=16 PV A-operand.
__global__ __launch_bounds__(256) void qkv_gemm_kernel(
    const unsigned short* __restrict__ X,
    const unsigned short* __restrict__ Wq, const unsigned short* __restrict__ Wk,
    const unsigned short* __restrict__ Wv,
    const float* __restrict__ bq, const float* __restrict__ bk, const float* __restrict__ bv,
    unsigned short* __restrict__ Qo, unsigned short* __restrict__ K2o, unsigned short* __restrict__ Vbo)
{
  __shared__ unsigned short As[128 * 32];
  __shared__ unsigned short Bs[128 * 32];
  const int zsel = blockIdx.z;
  const unsigned short* W = (zsel == 0) ? Wq : (zsel == 1) ? Wk : Wv;
  const float* bias        = (zsel == 0) ? bq : (zsel == 1) ? bk : bv;
  const int row0 = blockIdx.x * 128, col0 = blockIdx.y * 128;
  f32x4 acc[4][4];
  gemm128(X, W, As, Bs, acc, row0, col0);

  const int tid = threadIdx.x;
  const int wave = tid >> 6, lane = tid & 63, quad = lane >> 4, l16 = lane & 15;
  const int wr = (wave >> 1) * 64, wc = (wave & 1) * 64;

  if (zsel == 0) {
    const float osc = 0.18033688011112042f;   // log2(e)/8
    #pragma unroll
    for (int j = 0; j < 4; j++) {
      int n = col0 + wc + j * 16 + l16;
      float bb = bias[n];
      int h = n >> 6, d = n & 63;
      #pragma unroll
      for (int i = 0; i < 4; i++)
        #pragma unroll
        for (int rr = 0; rr < 4; rr++) {
          int s = row0 + wr + i * 16 + quad * 4 + rr;
          Qo[(size_t)(h * S + s) * DH + d] = f2bf((acc[i][j][rr] + bb) * osc);
        }
    }
  } else if (zsel == 1) {
    #pragma unroll
    for (int j = 0; j < 4; j++) {
      int n = col0 + wc + j * 16 + l16;
      float bb = bias[n];
      int h = n >> 6, dh = n & 63;
      int c = dh >> 4, hfk = (dh >> 3) & 1, j8 = dh & 7;
      #pragma unroll
      for (int i = 0; i < 4; i++)
        #pragma unroll
        for (int rr = 0; rr < 4; rr++) {
          int s = row0 + wr + i * 16 + quad * 4 + rr;
          int g = s >> 5, l32k = s & 31;
          K2o[((size_t)((h * 128 + g) * 4 + c) * 64 + hfk * 32 + l32k) * 8 + j8] =
              f2bf(acc[i][j][rr] + bb);
        }
    }
  } else {
    // m = key&15 = quad*4+rr -> hf_v = quad&1, j = (quad>>1)*4 + rr, grp = i&1
    #pragma unroll
    for (int j = 0; j < 4; j++) {
      int n = col0 + wc + j * 16 + l16;
      float bb = bias[n];
      int h = n >> 6, dh = n & 63;
      int ng = dh >> 5, l32v = dh & 31;
      int hf_v = quad & 1, jj0 = (quad >> 1) * 4;
      #pragma unroll
      for (int i = 0; i < 4; i++) {
        int gt = (row0 + wr + i * 16) >> 5;
        int grp = i & 1;
        ushort4 pv;
        pv.x = f2bf(acc[i][j][0] + bb); pv.y = f2bf(acc[i][j][1] + bb);
        pv.z = f2bf(acc[i][j][2] + bb); pv.w = f2bf(acc[i][j][3] + bb);
        *reinterpret_cast<ushort4*>(
            Vbo + ((size_t)(((h * 128 + gt) * 2 + grp) * 2 + ng) * 64 + hf_v * 32 + l32v) * 8 + jj0) = pv;
      }
    }
  }
}

// out = A @ W^T + bias_eff
__global__ __launch_bounds__(256) void out_gemm_kernel(
    const unsigned short* __restrict__ A, const unsigned short* __restrict__ W,
    const float* __restrict__ be, float* __restrict__ dst)
{
  __shared__ unsigned short As[128 * 32];
  __shared__ unsigned short Bs[128 * 32];
  const int row0 = blockIdx.x * 128, col0 = blockIdx.y * 128;
  f32x4 acc[4][4];
  gemm128(A, W, As, Bs, acc, row0, col0);

  const int tid = threadIdx.x;
  const int wave = tid >> 6, lane = tid & 63, quad = lane >> 4, l16 = lane & 15;
  const int wr = (wave >> 1) * 64, wc = (wave & 1) * 64;
  #pragma unroll
  for (int j = 0; j < 4; j++) {
    int n = col0 + wc + j * 16 + l16;
    float bb = be[n];
    #pragma unroll
    for (int i = 0; i < 4; i++)
      #pragma unroll
      for (int rr = 0; rr < 4; rr++) {
        int s = row0 + wr + i * 16 + quad * 4 + rr;
        dst[(size_t)s * HID + n] = acc[i][j][rr] + bb;
      }
  }
}

// VsumP[p][h*64+d] = partial sum of V over gt range (new Vb layout; perm-invariant)
__global__ __launch_bounds__(256) void vsum_kernel(
    const unsigned short* __restrict__ Vb, float* __restrict__ VsumP)
{
  __shared__ float red[256];
  const int p = blockIdx.x, h = blockIdx.y, tid = threadIdx.x;
  const int d = tid & 63, chunk = tid >> 6;
  const int ng = d >> 5, l32 = d & 31;
  float s = 0.f;
  for (int m = 0; m < 4; m++) {
    int gt = p * 16 + chunk * 4 + m;
    #pragma unroll
    for (int grp = 0; grp < 2; grp++)
      #pragma unroll
      for (int hf = 0; hf < 2; hf++) {
        uint4 u = *reinterpret_cast<const uint4*>(
            Vb + ((size_t)(((h * 128 + gt) * 2 + grp) * 2 + ng) * 64 + hf * 32 + l32) * 8);
        const unsigned int w[4] = {u.x, u.y, u.z, u.w};
        #pragma unroll
        for (int q = 0; q < 4; q++) {
          s += __builtin_bit_cast(float, w[q] << 16);
          s += __builtin_bit_cast(float, w[q] & 0xFFFF0000u);
        }
      }
  }
  red[tid] = s;
  __syncthreads();
  if (tid < 64)
    VsumP[p * 1024 + h * 64 + tid] = red[tid] + red[64 + tid] + red[128 + tid] + red[192 + tid];
}

// be[n] = bo[n] + (Vsum . wo[n,:]) / 4097, Vsum = sum of 8 partials
__global__ __launch_bounds__(256) void biasfold_kernel(
    const float* __restrict__ VsumP, const float* __restrict__ wo,
    const float* __restrict__ bo, float* __restrict__ be)
{
  const int n = blockIdx.x * 4 + (threadIdx.x >> 6);
  const int l = threadIdx.x & 63;
  float acc = 0.f;
  #pragma unroll
  for (int i = 0; i < 16; i++) {
    float vs = 0.f;
    #pragma unroll
    for (int p = 0; p < 8; p++) vs += VsumP[p * 1024 + l + 64 * i];
    acc += vs * wo[(size_t)n * HID + l + 64 * i];
  }
  #pragma unroll
  for (int off = 32; off >= 1; off >>= 1) acc += __shfl_xor(acc, off);
  if (l == 0) be[n] = bo[n] + acc * (1.f / 4097.f);
}

// ---------------------------------------------------------------- attention v9b
// Collapsed double softmax (w = 1+p): out = (Vsum + softmax1(S)V)/4097.
// PV via FULL-RATE 32x32x16 MFMA; K/V frag-packed so reg-octets feed MFMA.
// v9b: K/V tiles staged into LDS via global_load_lds (zero VGPR cost),
//     double-buffered, one barrier per iteration. Both qc-waves of a ks-half
//     consume the same LDS tile -> L2 read traffic halved, and demand-load
//     stalls become async prefetch drained at the barrier (overlap window =
//     full compute phase).
//     FIX vs v9: LDS destination of global_load_lds is now WAVE-UNIFORM
//     (HW applies +lane*16B itself; per-lane LDS ptr is undefined behavior
//     and the suspected cause of the round-3 container failure).
//   v8 evidence: 96us, MfmaUtil 31%, L2 traffic ~22TB/s (~63% of ceiling),
//   both pipes idle ~65% of time -> L2-latency/queuing bound, not residency.
// LDS: tiles 2(dbuf) x 2(ks) x (K 4KB + V 4KB) = 32KB; epilogue Ol/Z1l
// (16.9KB) aliases the dead tile buffers. 4 blocks/CU preserved.
__global__ __launch_bounds__(256, 4) void attn_kernel(
    const unsigned short* __restrict__ Q, const unsigned short* __restrict__ K2,
    const unsigned short* __restrict__ Vb, unsigned short* __restrict__ OUT)
{
  __shared__ unsigned short Tiles[2][2][2][2048];   // [dbuf][ks][K|V][2048 shorts]
  float* Ol  = reinterpret_cast<float*>(&Tiles[0][0][0][0]);              // [2][32][64]
  float* Z1l = reinterpret_cast<float*>(
      reinterpret_cast<char*>(&Tiles[0][0][0][0]) + 16384);               // [128]

  // XCD-aware remap: hardware assigns XCD = linear_block_id % 8 (round-robin).
  // Remap so XCD x owns heads {2x, 2x+1}: its K2+Vb working set = 2MB (L2-fit).
  const int lin = blockIdx.y * 64 + blockIdx.x;
  const int xcd = lin & 7, idx = lin >> 3;
  const int h = xcd * 2 + (idx >> 6);
  const int q0 = (idx & 63) * 64;

  const int tid = threadIdx.x;
  const int wave = tid >> 6, lane = tid & 63, hf = lane >> 5, l32 = lane & 31;
  const int qc = wave & 1, ks = wave >> 1;

  // Q B-frags (K=16 QK): B[k=c*16+hf*8+j][n=q=l32]
  short8 qf[4];
  {
    const unsigned short* qrow = Q + (size_t)(h * S + q0 + qc * 32 + l32) * DH;
    #pragma unroll
    for (int c = 0; c < 4; c++)
      qf[c] = *reinterpret_cast<const short8*>(qrow + c * 16 + hf * 8);
  }

  float z1p = 0.f;
  f32x16 Oa[2];
  #pragma unroll
  for (int ng = 0; ng < 2; ng++)
    #pragma unroll
    for (int r = 0; r < 16; r++) Oa[ng][r] = 0.f;

  const unsigned short* Kb = K2 + (size_t)h * 128 * 4 * 64 * 8;
  const unsigned short* Vbb = Vb + (size_t)h * 128 * 4 * 64 * 8;

  // Staging roles: wave w stages tile (sks = w>>1, sv = w&1).
  // K tile g and V tile g are both contiguous 2048-short (4KB) blocks at g*2048.
  // Global src carries the per-lane +lane*8; LDS dest is wave-uniform.
  const int sks = wave >> 1, sv = wave & 1;
  const unsigned short* gsrc =
      (sv ? Vbb : Kb) + (size_t)sks * 64 * 2048 + (size_t)lane * 8;
  unsigned short* ldsbase = &Tiles[0][sks][sv][0];   // wave-uniform

  // prologue: stage gl=0 into buf 0
  #pragma unroll
  for (int i = 0; i < 4; i++)
    gload16(gsrc + i * 512, ldsbase + i * 512);
  __syncthreads();

  int buf = 0;
  for (int gl = 0; gl < 64; gl++) {
    // async-stage next tile into the other buffer (no VGPR cost)
    if (gl + 1 < 64) {
      const unsigned short* s = gsrc + (size_t)(gl + 1) * 2048;
      unsigned short* d = ldsbase + (buf ^ 1) * (2 * 2 * 2048);
      #pragma unroll
      for (int i = 0; i < 4; i++)
        gload16(s + i * 512, d + i * 512);
    }

    const unsigned short* TK = &Tiles[buf][ks][0][0];
    const unsigned short* TV = &Tiles[buf][ks][1][0];

    // K A-frags from LDS: A[m=key=l32][k=c*16+hf*8+j]
    short8 kf[4];
    #pragma unroll
    for (int c = 0; c < 4; c++)
      kf[c] = *reinterpret_cast<const short8*>(TK + (c * 64 + lane) * 8);
    // V B-frags from LDS (K=16, relabeled keys): B[k=hf*8+j][n=d=ng*32+l32]
    short8 vfr[2][2];
    #pragma unroll
    for (int grp = 0; grp < 2; grp++)
      #pragma unroll
      for (int ng = 0; ng < 2; ng++)
        vfr[grp][ng] = *reinterpret_cast<const short8*>(
            TV + ((grp * 2 + ng) * 64 + lane) * 8);

    // S^T tile: 32 keys x 32 q (C: col=q=l32, row=key=(reg&3)+4hf+8(reg>>2))
    f32x16 acc;
    #pragma unroll
    for (int r = 0; r < 16; r++) acc[r] = 0.f;
    #pragma unroll
    for (int c = 0; c < 4; c++)
      acc = __builtin_amdgcn_mfma_f32_32x32x16_bf16(kf[c], qf[c], acc, 0, 0, 0);

    // exp + pack: reg-octet [0..7] / [8..15] become K=16 A-operands directly
    unsigned int D[8];
    #pragma unroll
    for (int m = 0; m < 8; m++) {
      float t0 = __builtin_amdgcn_exp2f(acc[2 * m]);
      float t1 = __builtin_amdgcn_exp2f(acc[2 * m + 1]);
      z1p += t0 + t1;
      D[m] = pktrunc(t0, t1);
    }
    u32x4 d0 = {D[0], D[1], D[2], D[3]};
    u32x4 d1 = {D[4], D[5], D[6], D[7]};
    short8 A0 = __builtin_bit_cast(short8, d0);
    short8 A1 = __builtin_bit_cast(short8, d1);

    Oa[0] = __builtin_amdgcn_mfma_f32_32x32x16_bf16(A0, vfr[0][0], Oa[0], 0, 0, 0);
    Oa[1] = __builtin_amdgcn_mfma_f32_32x32x16_bf16(A0, vfr[0][1], Oa[1], 0, 0, 0);
    Oa[0] = __builtin_amdgcn_mfma_f32_32x32x16_bf16(A1, vfr[1][0], Oa[0], 0, 0, 0);
    Oa[1] = __builtin_amdgcn_mfma_f32_32x32x16_bf16(A1, vfr[1][1], Oa[1], 0, 0, 0);

    // one barrier: drains this wave's staging (vmcnt) + all waves done
    // reading Tiles[buf] before it is overwritten next iteration
    __syncthreads();
    buf ^= 1;
  }

  // ---- epilogue (Tiles dead after final barrier; Ol/Z1l alias them) ----
  {
    float z1 = z1p + __shfl_xor(z1p, 32);
    if (hf == 0) Z1l[ks * 64 + qc * 32 + l32] = z1;
  }
  if (ks == 0) {
    #pragma unroll
    for (int reg = 0; reg < 16; reg++) {
      const int row = (reg & 3) + 8 * (reg >> 2) + 4 * hf;
      #pragma unroll
      for (int ng = 0; ng < 2; ng++)
        Ol[(qc * 32 + row) * 64 + ng * 32 + l32] = Oa[ng][reg];
    }
  }
  __syncthreads();
  if (ks == 1) {
    #pragma unroll
    for (int reg = 0; reg < 16; reg++) {
      const int row = (reg & 3) + 8 * (reg >> 2) + 4 * hf;
      const int ql = qc * 32 + row;
      const float rz = 1.f / ((Z1l[ql] + Z1l[64 + ql]) * 4097.f);
      const int s = q0 + ql;
      #pragma unroll
      for (int ng = 0; ng < 2; ng++) {
        const float o = Ol[(qc * 32 + row) * 64 + ng * 32 + l32] + Oa[ng][reg];
        OUT[(size_t)s * HID + h * DH + ng * 32 + l32] = f2bf(o * rz);
      }
    }
  }
}

// ----------------------------------------------------------------
extern "C" void kernel_launch(void* const* d_in, const int* in_sizes, int n_in,
                              void* d_out, int out_size, void* d_ws, size_t ws_size,
                              hipStream_t stream) {
  const float* x  = (const float*)d_in[0];
  const float* wq = (const float*)d_in[1];
  const float* bq = (const float*)d_in[2];
  const float* wk = (const float*)d_in[3];
  const float* bk = (const float*)d_in[4];
  const float* wv = (const float*)d_in[5];
  const float* bv = (const float*)d_in[6];
  const float* wo = (const float*)d_in[7];
  const float* bo = (const float*)d_in[8];
  float* out = (float*)d_out;

  char* ws = (char*)d_ws;
  unsigned short* xb  = (unsigned short*)(ws);                 // 8 MB (reused for attn out)
  unsigned short* wqb = (unsigned short*)(ws + (8u  << 20));
  unsigned short* wkb = (unsigned short*)(ws + (10u << 20));
  unsigned short* wvb = (unsigned short*)(ws + (12u << 20));
  unsigned short* wob = (unsigned short*)(ws + (14u << 20));
  unsigned short* qw  = (unsigned short*)(ws + (16u << 20));   // [H][S][64] prescaled
  unsigned short* k2  = (unsigned short*)(ws + (24u << 20));   // frag-packed K (K=16 A-op)
  unsigned short* vb  = (unsigned short*)(ws + (32u << 20));   // frag-packed V (K=16 B-op, relabeled)
  float* vsump        = (float*)(ws + (40u << 20));            // [8][1024]
  float* be           = (float*)(ws + (40u << 20) + 65536);    // [1024]
  unsigned short* aw  = xb;

  cast_kernel<<<dim3(4096, 5), 256, 0, stream>>>(x, wq, wk, wv, wo, xb, wqb, wkb, wvb, wob);
  qkv_gemm_kernel<<<dim3(32, 8, 3), 256, 0, stream>>>(xb, wqb, wkb, wvb, bq, bk, bv, qw, k2, vb);
  vsum_kernel<<<dim3(8, 16), 256, 0, stream>>>(vb, vsump);
  biasfold_kernel<<<dim3(256), 256, 0, stream>>>(vsump, wo, bo, be);
  attn_kernel<<<dim3(64, 16), 256, 0, stream>>>(qw, k2, vb, aw);
  out_gemm_kernel<<<dim3(32, 8, 1), 256, 0, stream>>>(aw, wob, be, out);
}

// Round 5
// 242.502 us; speedup vs baseline: 1.0419x; 1.0419x over previous
//
#include <hip/hip_runtime.h>
#include <hip/hip_bf16.h>
#include <stdint.h>

#define S 4096
#define HID 1024
#define NH 16
#define DH 64

typedef __attribute__((ext_vector_type(8))) short short8;
typedef __attribute__((ext_vector_type(2))) float f32x2;
typedef __attribute__((ext_vector_type(4))) float f32x4;
typedef __attribute__((ext_vector_type(16))) float f32x16;
typedef __attribute__((ext_vector_type(4))) unsigned int u32x4;

__device__ __forceinline__ unsigned short f2bf(float f) {
  unsigned int u = __builtin_bit_cast(unsigned int, f);
  u += 0x7FFF + ((u >> 16) & 1);   // round-to-nearest-even
  return (unsigned short)(u >> 16);
}
// pack two fp32 -> bf16x2 dword by truncation (1 v_perm_b32)
__device__ __forceinline__ unsigned int pktrunc(float lo, float hi) {
  return __builtin_amdgcn_perm(__builtin_bit_cast(unsigned int, hi),
                               __builtin_bit_cast(unsigned int, lo), 0x07060302u);
}
// async global->LDS, 16B per lane. LDS pointer MUST be wave-uniform;
// HW writes lane i at ldsbase + i*16B (m104/m108 semantics).
__device__ __forceinline__ void gload16(const unsigned short* g, unsigned short* l) {
  __builtin_amdgcn_global_load_lds((const __attribute__((address_space(1))) unsigned int*)g,
                                   (__attribute__((address_space(3))) unsigned int*)l, 16, 0, 0);
}

// ---------------------------------------------------------------- cast fp32 -> bf16
__global__ __launch_bounds__(256) void cast_kernel(
    const float* __restrict__ x,  const float* __restrict__ wq,
    const float* __restrict__ wk, const float* __restrict__ wv,
    const float* __restrict__ wo,
    unsigned short* __restrict__ xb,  unsigned short* __restrict__ wqb,
    unsigned short* __restrict__ wkb, unsigned short* __restrict__ wvb,
    unsigned short* __restrict__ wob)
{
  int y = blockIdx.y;
  const float* src; unsigned short* dst; int n;
  if      (y == 0) { src = x;  dst = xb;  n = S * HID; }
  else if (y == 1) { src = wq; dst = wqb; n = HID * HID; }
  else if (y == 2) { src = wk; dst = wkb; n = HID * HID; }
  else if (y == 3) { src = wv; dst = wvb; n = HID * HID; }
  else             { src = wo; dst = wob; n = HID * HID; }
  int i = (blockIdx.x * 256 + threadIdx.x) * 4;
  if (i < n) {
    float4 v = *reinterpret_cast<const float4*>(src + i);
    ushort4 o;
    o.x = f2bf(v.x); o.y = f2bf(v.y); o.z = f2bf(v.z); o.w = f2bf(v.w);
    *reinterpret_cast<ushort4*>(dst + i) = o;
  }
}

// ---------------------------------------------------------------- 128x128 NT GEMM core (m97-style)
__device__ __forceinline__ void gemm128(
    const unsigned short* __restrict__ A, const unsigned short* __restrict__ W,
    unsigned short* As, unsigned short* Bs, f32x4 acc[4][4], int row0, int col0)
{
  const int tid = threadIdx.x;
  const int wave = tid >> 6, lane = tid & 63, quad = lane >> 4, l16 = lane & 15;
  const int wr = (wave >> 1) * 64, wc = (wave & 1) * 64;
  const int srow = lane >> 2, sseg = lane & 3;
  const f32x4 z = {0.f, 0.f, 0.f, 0.f};
  #pragma unroll
  for (int i = 0; i < 4; i++)
    #pragma unroll
    for (int j = 0; j < 4; j++) acc[i][j] = z;

  for (int k0 = 0; k0 < HID; k0 += 32) {
    __syncthreads();
    #pragma unroll
    for (int c = 0; c < 2; c++) {
      const int rbase = c * 64 + wave * 16;
      gload16(A + (size_t)(row0 + rbase + srow) * HID + k0 + sseg * 8, As + rbase * 32);
      gload16(W + (size_t)(col0 + rbase + srow) * HID + k0 + sseg * 8, Bs + rbase * 32);
    }
    __syncthreads();

    short8 af[4], bfr[4];
    #pragma unroll
    for (int i = 0; i < 4; i++)
      af[i] = *reinterpret_cast<const short8*>(As + (wr + i * 16 + l16) * 32 + quad * 8);
    #pragma unroll
    for (int j = 0; j < 4; j++)
      bfr[j] = *reinterpret_cast<const short8*>(Bs + (wc + j * 16 + l16) * 32 + quad * 8);
    #pragma unroll
    for (int i = 0; i < 4; i++)
      #pragma unroll
      for (int j = 0; j < 4; j++)
        acc[i][j] = __builtin_amdgcn_mfma_f32_16x16x32_bf16(af[i], bfr[j], acc[i][j], 0, 0, 0);
  }
}

// QKV projections. Q -> [H][S][64] prescaled by log2e/8.
// K -> K2 frag-packed (K=16 A-op): K2[(((h*128+g)*4+c)*64 + lane)*8 + j]
// V -> Vb frag-packed (K=16 B-op with keys bitswap23-relabeled):
//      Vb[((((h*128+gt)*2+grp)*2+ng)*64 + hf*32 + l32)*8 + j]
//      holds V[key = gt*32+grp*16+bitswap23(hf*8+j)][d = ng*32+l32]
//      so that the S^T C-layout reg-octet IS a valid K=16 PV A-operand.
__global__ __launch_bounds__(256) void qkv_gemm_kernel(
    const unsigned short* __restrict__ X,
    const unsigned short* __restrict__ Wq, const unsigned short* __restrict__ Wk,
    const unsigned short* __restrict__ Wv,
    const float* __restrict__ bq, const float* __restrict__ bk, const float* __restrict__ bv,
    unsigned short* __restrict__ Qo, unsigned short* __restrict__ K2o, unsigned short* __restrict__ Vbo)
{
  __shared__ unsigned short As[128 * 32];
  __shared__ unsigned short Bs[128 * 32];
  const int zsel = blockIdx.z;
  const unsigned short* W = (zsel == 0) ? Wq : (zsel == 1) ? Wk : Wv;
  const float* bias        = (zsel == 0) ? bq : (zsel == 1) ? bk : bv;
  const int row0 = blockIdx.x * 128, col0 = blockIdx.y * 128;
  f32x4 acc[4][4];
  gemm128(X, W, As, Bs, acc, row0, col0);

  const int tid = threadIdx.x;
  const int wave = tid >> 6, lane = tid & 63, quad = lane >> 4, l16 = lane & 15;
  const int wr = (wave >> 1) * 64, wc = (wave & 1) * 64;

  if (zsel == 0) {
    const float osc = 0.18033688011112042f;   // log2(e)/8
    #pragma unroll
    for (int j = 0; j < 4; j++) {
      int n = col0 + wc + j * 16 + l16;
      float bb = bias[n];
      int h = n >> 6, d = n & 63;
      #pragma unroll
      for (int i = 0; i < 4; i++)
        #pragma unroll
        for (int rr = 0; rr < 4; rr++) {
          int s = row0 + wr + i * 16 + quad * 4 + rr;
          Qo[(size_t)(h * S + s) * DH + d] = f2bf((acc[i][j][rr] + bb) * osc);
        }
    }
  } else if (zsel == 1) {
    #pragma unroll
    for (int j = 0; j < 4; j++) {
      int n = col0 + wc + j * 16 + l16;
      float bb = bias[n];
      int h = n >> 6, dh = n & 63;
      int c = dh >> 4, hfk = (dh >> 3) & 1, j8 = dh & 7;
      #pragma unroll
      for (int i = 0; i < 4; i++)
        #pragma unroll
        for (int rr = 0; rr < 4; rr++) {
          int s = row0 + wr + i * 16 + quad * 4 + rr;
          int g = s >> 5, l32k = s & 31;
          K2o[((size_t)((h * 128 + g) * 4 + c) * 64 + hfk * 32 + l32k) * 8 + j8] =
              f2bf(acc[i][j][rr] + bb);
        }
    }
  } else {
    // m = key&15 = quad*4+rr -> hf_v = quad&1, j = (quad>>1)*4 + rr, grp = i&1
    #pragma unroll
    for (int j = 0; j < 4; j++) {
      int n = col0 + wc + j * 16 + l16;
      float bb = bias[n];
      int h = n >> 6, dh = n & 63;
      int ng = dh >> 5, l32v = dh & 31;
      int hf_v = quad & 1, jj0 = (quad >> 1) * 4;
      #pragma unroll
      for (int i = 0; i < 4; i++) {
        int gt = (row0 + wr + i * 16) >> 5;
        int grp = i & 1;
        ushort4 pv;
        pv.x = f2bf(acc[i][j][0] + bb); pv.y = f2bf(acc[i][j][1] + bb);
        pv.z = f2bf(acc[i][j][2] + bb); pv.w = f2bf(acc[i][j][3] + bb);
        *reinterpret_cast<ushort4*>(
            Vbo + ((size_t)(((h * 128 + gt) * 2 + grp) * 2 + ng) * 64 + hf_v * 32 + l32v) * 8 + jj0) = pv;
      }
    }
  }
}

// out = A @ W^T + bias_eff
__global__ __launch_bounds__(256) void out_gemm_kernel(
    const unsigned short* __restrict__ A, const unsigned short* __restrict__ W,
    const float* __restrict__ be, float* __restrict__ dst)
{
  __shared__ unsigned short As[128 * 32];
  __shared__ unsigned short Bs[128 * 32];
  const int row0 = blockIdx.x * 128, col0 = blockIdx.y * 128;
  f32x4 acc[4][4];
  gemm128(A, W, As, Bs, acc, row0, col0);

  const int tid = threadIdx.x;
  const int wave = tid >> 6, lane = tid & 63, quad = lane >> 4, l16 = lane & 15;
  const int wr = (wave >> 1) * 64, wc = (wave & 1) * 64;
  #pragma unroll
  for (int j = 0; j < 4; j++) {
    int n = col0 + wc + j * 16 + l16;
    float bb = be[n];
    #pragma unroll
    for (int i = 0; i < 4; i++)
      #pragma unroll
      for (int rr = 0; rr < 4; rr++) {
        int s = row0 + wr + i * 16 + quad * 4 + rr;
        dst[(size_t)s * HID + n] = acc[i][j][rr] + bb;
      }
  }
}

// VsumP[p][h*64+d] = partial sum of V over gt range (new Vb layout; perm-invariant)
__global__ __launch_bounds__(256) void vsum_kernel(
    const unsigned short* __restrict__ Vb, float* __restrict__ VsumP)
{
  __shared__ float red[256];
  const int p = blockIdx.x, h = blockIdx.y, tid = threadIdx.x;
  const int d = tid & 63, chunk = tid >> 6;
  const int ng = d >> 5, l32 = d & 31;
  float s = 0.f;
  for (int m = 0; m < 4; m++) {
    int gt = p * 16 + chunk * 4 + m;
    #pragma unroll
    for (int grp = 0; grp < 2; grp++)
      #pragma unroll
      for (int hf = 0; hf < 2; hf++) {
        uint4 u = *reinterpret_cast<const uint4*>(
            Vb + ((size_t)(((h * 128 + gt) * 2 + grp) * 2 + ng) * 64 + hf * 32 + l32) * 8);
        const unsigned int w[4] = {u.x, u.y, u.z, u.w};
        #pragma unroll
        for (int q = 0; q < 4; q++) {
          s += __builtin_bit_cast(float, w[q] << 16);
          s += __builtin_bit_cast(float, w[q] & 0xFFFF0000u);
        }
      }
  }
  red[tid] = s;
  __syncthreads();
  if (tid < 64)
    VsumP[p * 1024 + h * 64 + tid] = red[tid] + red[64 + tid] + red[128 + tid] + red[192 + tid];
}

// be[n] = bo[n] + (Vsum . wo[n,:]) / 4097, Vsum = sum of 8 partials
__global__ __launch_bounds__(256) void biasfold_kernel(
    const float* __restrict__ VsumP, const float* __restrict__ wo,
    const float* __restrict__ bo, float* __restrict__ be)
{
  const int n = blockIdx.x * 4 + (threadIdx.x >> 6);
  const int l = threadIdx.x & 63;
  float acc = 0.f;
  #pragma unroll
  for (int i = 0; i < 16; i++) {
    float vs = 0.f;
    #pragma unroll
    for (int p = 0; p < 8; p++) vs += VsumP[p * 1024 + l + 64 * i];
    acc += vs * wo[(size_t)n * HID + l + 64 * i];
  }
  #pragma unroll
  for (int off = 32; off >= 1; off >>= 1) acc += __shfl_xor(acc, off);
  if (l == 0) be[n] = bo[n] + acc * (1.f / 4097.f);
}

// ---------------------------------------------------------------- attention v10
// Collapsed double softmax (w = 1+p): out = (Vsum + softmax1(S)V)/4097.
// PV via FULL-RATE 32x32x16 MFMA; K/V frag-packed so reg-octets feed MFMA.
// v10 = v9b + VALU strip-down (v9b counters: VALUBusy 47% = 42us > MFMA 32us,
// combined 83% -> VALU-bound, exp is only ~14us of the 42):
//   - main loop unrolled x2 with compile-time BUF: all 8 ds_read_b128 and
//     staging dests become base + 16-bit immediate offset; stage branch gone
//   - persistent zero tuple zacc: acc = mfma(kf0,qf0,zacc) kills 16 v_mov/iter
//   - packed z accumulation (f32x2 -> v_pk_add_f32) halves z-adds
// LDS: tiles 2(dbuf) x 2(ks) x (K 4KB + V 4KB) = 32KB; epilogue Ol/Z1l
// aliases the dead tile buffers. 4 blocks/CU.
struct AttnState {
  short8 qf[4];
  f32x16 Oa[2];
  f32x16 zacc;
  f32x2  zp;
};

template<int BUF>
__device__ __forceinline__ void attn_compute(
    const unsigned short* kbase, const unsigned short* vbase, AttnState& st)
{
  // K A-frags from LDS: A[m=key=l32][k=c*16+hf*8+j]  (offsets compile-time)
  short8 kf[4], vfr[4];
  #pragma unroll
  for (int c = 0; c < 4; c++)
    kf[c] = *reinterpret_cast<const short8*>(kbase + BUF * 8192 + c * 512);
  // V B-frags (K=16, relabeled keys): w = grp*2+ng
  #pragma unroll
  for (int w = 0; w < 4; w++)
    vfr[w] = *reinterpret_cast<const short8*>(vbase + BUF * 8192 + w * 512);

  // S^T tile: 32 keys x 32 q (C: col=q=l32, row=key=(reg&3)+4hf+8(reg>>2))
  f32x16 acc = __builtin_amdgcn_mfma_f32_32x32x16_bf16(kf[0], st.qf[0], st.zacc, 0, 0, 0);
  #pragma unroll
  for (int c = 1; c < 4; c++)
    acc = __builtin_amdgcn_mfma_f32_32x32x16_bf16(kf[c], st.qf[c], acc, 0, 0, 0);

  // exp + pack: reg-octet [0..7] / [8..15] become K=16 A-operands directly
  unsigned int D[8];
  #pragma unroll
  for (int m = 0; m < 8; m++) {
    float t0 = __builtin_amdgcn_exp2f(acc[2 * m]);
    float t1 = __builtin_amdgcn_exp2f(acc[2 * m + 1]);
    f32x2 t = {t0, t1};
    st.zp += t;                      // v_pk_add_f32
    D[m] = pktrunc(t0, t1);
  }
  u32x4 d0 = {D[0], D[1], D[2], D[3]};
  u32x4 d1 = {D[4], D[5], D[6], D[7]};
  short8 A0 = __builtin_bit_cast(short8, d0);
  short8 A1 = __builtin_bit_cast(short8, d1);

  st.Oa[0] = __builtin_amdgcn_mfma_f32_32x32x16_bf16(A0, vfr[0], st.Oa[0], 0, 0, 0);
  st.Oa[1] = __builtin_amdgcn_mfma_f32_32x32x16_bf16(A0, vfr[1], st.Oa[1], 0, 0, 0);
  st.Oa[0] = __builtin_amdgcn_mfma_f32_32x32x16_bf16(A1, vfr[2], st.Oa[0], 0, 0, 0);
  st.Oa[1] = __builtin_amdgcn_mfma_f32_32x32x16_bf16(A1, vfr[3], st.Oa[1], 0, 0, 0);
}

__device__ __forceinline__ void stage4(const unsigned short* gs, unsigned short* ldst) {
  #pragma unroll
  for (int i = 0; i < 4; i++)
    gload16(gs + i * 512, ldst + i * 512);
}

__global__ __launch_bounds__(256, 4) void attn_kernel(
    const unsigned short* __restrict__ Q, const unsigned short* __restrict__ K2,
    const unsigned short* __restrict__ Vb, unsigned short* __restrict__ OUT)
{
  __shared__ unsigned short T[2][2][2][2048];   // [dbuf][ks][K|V][2048 shorts]
  float* Ol  = reinterpret_cast<float*>(&T[0][0][0][0]);              // [2][32][64]
  float* Z1l = reinterpret_cast<float*>(
      reinterpret_cast<char*>(&T[0][0][0][0]) + 16384);               // [128]

  // XCD-aware remap: XCD x owns heads {2x,2x+1}: K2+Vb working set 2MB (L2-fit).
  const int lin = blockIdx.y * 64 + blockIdx.x;
  const int xcd = lin & 7, idx = lin >> 3;
  const int h = xcd * 2 + (idx >> 6);
  const int q0 = (idx & 63) * 64;

  const int tid = threadIdx.x;
  const int wave = tid >> 6, lane = tid & 63, hf = lane >> 5, l32 = lane & 31;
  const int qc = wave & 1, ks = wave >> 1;

  AttnState st;
  // Q B-frags (K=16 QK): B[k=c*16+hf*8+j][n=q=l32]
  {
    const unsigned short* qrow = Q + (size_t)(h * S + q0 + qc * 32 + l32) * DH;
    #pragma unroll
    for (int c = 0; c < 4; c++)
      st.qf[c] = *reinterpret_cast<const short8*>(qrow + c * 16 + hf * 8);
  }
  #pragma unroll
  for (int r = 0; r < 16; r++) { st.zacc[r] = 0.f; st.Oa[0][r] = 0.f; st.Oa[1][r] = 0.f; }
  st.zp = (f32x2){0.f, 0.f};

  const unsigned short* Kb = K2 + (size_t)h * 128 * 4 * 64 * 8;
  const unsigned short* Vbb = Vb + (size_t)h * 128 * 4 * 64 * 8;

  // Staging roles: wave w stages tile (sks = w>>1, sv = w&1); stagers of a
  // ks-half are exactly its consumers. Global src carries +lane*8; LDS dest
  // is wave-uniform.
  const int sks = wave >> 1, sv = wave & 1;
  const unsigned short* gs =
      (sv ? Vbb : Kb) + (size_t)sks * 64 * 2048 + (size_t)lane * 8;
  unsigned short* stT0 = &T[0][sks][sv][0];   // wave-uniform dests
  unsigned short* stT1 = &T[1][sks][sv][0];

  // per-lane LDS read bases (offsets added as compile-time immediates)
  const unsigned short* kbase = &T[0][ks][0][0] + lane * 8;
  const unsigned short* vbase = &T[0][ks][1][0] + lane * 8;

  // prologue: stage tile 0 into buf 0; gs then points at tile 1
  stage4(gs, stT0);
  gs += 2048;
  __syncthreads();

  // 31 full pairs: tiles (2t) from buf0 (staging 2t+1->buf1),
  //                tiles (2t+1) from buf1 (staging 2t+2->buf0)
  for (int t = 0; t < 31; t++) {
    stage4(gs, stT1); gs += 2048;
    attn_compute<0>(kbase, vbase, st);
    __syncthreads();
    stage4(gs, stT0); gs += 2048;
    attn_compute<1>(kbase, vbase, st);
    __syncthreads();
  }
  // tail: tile 62 from buf0 (staging 63->buf1), tile 63 from buf1
  stage4(gs, stT1);
  attn_compute<0>(kbase, vbase, st);
  __syncthreads();
  attn_compute<1>(kbase, vbase, st);
  __syncthreads();   // final: Tiles dead; Ol/Z1l aliasing is now safe

  // ---- epilogue ----
  {
    float z1p = st.zp[0] + st.zp[1];
    float z1 = z1p + __shfl_xor(z1p, 32);
    if (hf == 0) Z1l[ks * 64 + qc * 32 + l32] = z1;
  }
  if (ks == 0) {
    #pragma unroll
    for (int reg = 0; reg < 16; reg++) {
      const int row = (reg & 3) + 8 * (reg >> 2) + 4 * hf;
      #pragma unroll
      for (int ng = 0; ng < 2; ng++)
        Ol[(qc * 32 + row) * 64 + ng * 32 + l32] = st.Oa[ng][reg];
    }
  }
  __syncthreads();
  if (ks == 1) {
    #pragma unroll
    for (int reg = 0; reg < 16; reg++) {
      const int row = (reg & 3) + 8 * (reg >> 2) + 4 * hf;
      const int ql = qc * 32 + row;
      const float rz = 1.f / ((Z1l[ql] + Z1l[64 + ql]) * 4097.f);
      const int s = q0 + ql;
      #pragma unroll
      for (int ng = 0; ng < 2; ng++) {
        const float o = Ol[(qc * 32 + row) * 64 + ng * 32 + l32] + st.Oa[ng][reg];
        OUT[(size_t)s * HID + h * DH + ng * 32 + l32] = f2bf(o * rz);
      }
    }
  }
}

// ----------------------------------------------------------------
extern "C" void kernel_launch(void* const* d_in, const int* in_sizes, int n_in,
                              void* d_out, int out_size, void* d_ws, size_t ws_size,
                              hipStream_t stream) {
  const float* x  = (const float*)d_in[0];
  const float* wq = (const float*)d_in[1];
  const float* bq = (const float*)d_in[2];
  const float* wk = (const float*)d_in[3];
  const float* bk = (const float*)d_in[4];
  const float* wv = (const float*)d_in[5];
  const float* bv = (const float*)d_in[6];
  const float* wo = (const float*)d_in[7];
  const float* bo = (const float*)d_in[8];
  float* out = (float*)d_out;

  char* ws = (char*)d_ws;
  unsigned short* xb  = (unsigned short*)(ws);                 // 8 MB (reused for attn out)
  unsigned short* wqb = (unsigned short*)(ws + (8u  << 20));
  unsigned short* wkb = (unsigned short*)(ws + (10u << 20));
  unsigned short* wvb = (unsigned short*)(ws + (12u << 20));
  unsigned short* wob = (unsigned short*)(ws + (14u << 20));
  unsigned short* qw  = (unsigned short*)(ws + (16u << 20));   // [H][S][64] prescaled
  unsigned short* k2  = (unsigned short*)(ws + (24u << 20));   // frag-packed K (K=16 A-op)
  unsigned short* vb  = (unsigned short*)(ws + (32u << 20));   // frag-packed V (K=16 B-op, relabeled)
  float* vsump        = (float*)(ws + (40u << 20));            // [8][1024]
  float* be           = (float*)(ws + (40u << 20) + 65536);    // [1024]
  unsigned short* aw  = xb;

  cast_kernel<<<dim3(4096, 5), 256, 0, stream>>>(x, wq, wk, wv, wo, xb, wqb, wkb, wvb, wob);
  qkv_gemm_kernel<<<dim3(32, 8, 3), 256, 0, stream>>>(xb, wqb, wkb, wvb, bq, bk, bv, qw, k2, vb);
  vsum_kernel<<<dim3(8, 16), 256, 0, stream>>>(vb, vsump);
  biasfold_kernel<<<dim3(256), 256, 0, stream>>>(vsump, wo, bo, be);
  attn_kernel<<<dim3(64, 16), 256, 0, stream>>>(qw, k2, vb, aw);
  out_gemm_kernel<<<dim3(32, 8, 1), 256, 0, stream>>>(aw, wob, be, out);
}

// Round 6
// 238.901 us; speedup vs baseline: 1.0576x; 1.0151x over previous
//
#include <hip/hip_runtime.h>
#include <hip/hip_bf16.h>
#include <stdint.h>

#define S 4096
#define HID 1024
#define NH 16
#define DH 64

typedef __attribute__((ext_vector_type(8))) short short8;
typedef __attribute__((ext_vector_type(2))) float f32x2;
typedef __attribute__((ext_vector_type(4))) float f32x4;
typedef __attribute__((ext_vector_type(16))) float f32x16;
typedef __attribute__((ext_vector_type(4))) unsigned int u32x4;

#define VMCNT8 asm volatile("s_waitcnt vmcnt(8)" ::: "memory")
#define VMCNT0 asm volatile("s_waitcnt vmcnt(0)" ::: "memory")

__device__ __forceinline__ unsigned short f2bf(float f) {
  unsigned int u = __builtin_bit_cast(unsigned int, f);
  u += 0x7FFF + ((u >> 16) & 1);   // round-to-nearest-even
  return (unsigned short)(u >> 16);
}
// pack two fp32 -> bf16x2 dword by truncation (1 v_perm_b32)
__device__ __forceinline__ unsigned int pktrunc(float lo, float hi) {
  return __builtin_amdgcn_perm(__builtin_bit_cast(unsigned int, hi),
                               __builtin_bit_cast(unsigned int, lo), 0x07060302u);
}
// async global->LDS, 16B per lane. LDS pointer MUST be wave-uniform;
// HW writes lane i at ldsbase + i*16B (m104/m108 semantics).
__device__ __forceinline__ void gload16(const unsigned short* g, unsigned short* l) {
  __builtin_amdgcn_global_load_lds((const __attribute__((address_space(1))) unsigned int*)g,
                                   (__attribute__((address_space(3))) unsigned int*)l, 16, 0, 0);
}

// ---------------------------------------------------------------- cast fp32 -> bf16
__global__ __launch_bounds__(256) void cast_kernel(
    const float* __restrict__ x,  const float* __restrict__ wq,
    const float* __restrict__ wk, const float* __restrict__ wv,
    const float* __restrict__ wo,
    unsigned short* __restrict__ xb,  unsigned short* __restrict__ wqb,
    unsigned short* __restrict__ wkb, unsigned short* __restrict__ wvb,
    unsigned short* __restrict__ wob)
{
  int y = blockIdx.y;
  const float* src; unsigned short* dst; int n;
  if      (y == 0) { src = x;  dst = xb;  n = S * HID; }
  else if (y == 1) { src = wq; dst = wqb; n = HID * HID; }
  else if (y == 2) { src = wk; dst = wkb; n = HID * HID; }
  else if (y == 3) { src = wv; dst = wvb; n = HID * HID; }
  else             { src = wo; dst = wob; n = HID * HID; }
  int i = (blockIdx.x * 256 + threadIdx.x) * 4;
  if (i < n) {
    float4 v = *reinterpret_cast<const float4*>(src + i);
    ushort4 o;
    o.x = f2bf(v.x); o.y = f2bf(v.y); o.z = f2bf(v.z); o.w = f2bf(v.w);
    *reinterpret_cast<ushort4*>(dst + i) = o;
  }
}

// ---------------------------------------------------------------- 128x128 NT GEMM core (m97-style)
__device__ __forceinline__ void gemm128(
    const unsigned short* __restrict__ A, const unsigned short* __restrict__ W,
    unsigned short* As, unsigned short* Bs, f32x4 acc[4][4], int row0, int col0)
{
  const int tid = threadIdx.x;
  const int wave = tid >> 6, lane = tid & 63, quad = lane >> 4, l16 = lane & 15;
  const int wr = (wave >> 1) * 64, wc = (wave & 1) * 64;
  const int srow = lane >> 2, sseg = lane & 3;
  const f32x4 z = {0.f, 0.f, 0.f, 0.f};
  #pragma unroll
  for (int i = 0; i < 4; i++)
    #pragma unroll
    for (int j = 0; j < 4; j++) acc[i][j] = z;

  for (int k0 = 0; k0 < HID; k0 += 32) {
    __syncthreads();
    #pragma unroll
    for (int c = 0; c < 2; c++) {
      const int rbase = c * 64 + wave * 16;
      gload16(A + (size_t)(row0 + rbase + srow) * HID + k0 + sseg * 8, As + rbase * 32);
      gload16(W + (size_t)(col0 + rbase + srow) * HID + k0 + sseg * 8, Bs + rbase * 32);
    }
    __syncthreads();

    short8 af[4], bfr[4];
    #pragma unroll
    for (int i = 0; i < 4; i++)
      af[i] = *reinterpret_cast<const short8*>(As + (wr + i * 16 + l16) * 32 + quad * 8);
    #pragma unroll
    for (int j = 0; j < 4; j++)
      bfr[j] = *reinterpret_cast<const short8*>(Bs + (wc + j * 16 + l16) * 32 + quad * 8);
    #pragma unroll
    for (int i = 0; i < 4; i++)
      #pragma unroll
      for (int j = 0; j < 4; j++)
        acc[i][j] = __builtin_amdgcn_mfma_f32_16x16x32_bf16(af[i], bfr[j], acc[i][j], 0, 0, 0);
  }
}

// QKV projections. Q -> [H][S][64] prescaled by log2e/8.
// K -> K2 frag-packed (K=16 A-op): K2[(((h*128+g)*4+c)*64 + lane)*8 + j]
// V -> Vb frag-packed (K=16 B-op with keys bitswap23-relabeled):
//      Vb[((((h*128+gt)*2+grp)*2+ng)*64 + hf*32 + l32)*8 + j]
//      holds V[key = gt*32+grp*16+bitswap23(hf*8+j)][d = ng*32+l32]
//      so that the S^T C-layout reg-octet IS a valid K=16 PV A-operand.
__global__ __launch_bounds__(256) void qkv_gemm_kernel(
    const unsigned short* __restrict__ X,
    const unsigned short* __restrict__ Wq, const unsigned short* __restrict__ Wk,
    const unsigned short* __restrict__ Wv,
    const float* __restrict__ bq, const float* __restrict__ bk, const float* __restrict__ bv,
    unsigned short* __restrict__ Qo, unsigned short* __restrict__ K2o, unsigned short* __restrict__ Vbo)
{
  __shared__ unsigned short As[128 * 32];
  __shared__ unsigned short Bs[128 * 32];
  const int zsel = blockIdx.z;
  const unsigned short* W = (zsel == 0) ? Wq : (zsel == 1) ? Wk : Wv;
  const float* bias        = (zsel == 0) ? bq : (zsel == 1) ? bk : bv;
  const int row0 = blockIdx.x * 128, col0 = blockIdx.y * 128;
  f32x4 acc[4][4];
  gemm128(X, W, As, Bs, acc, row0, col0);

  const int tid = threadIdx.x;
  const int wave = tid >> 6, lane = tid & 63, quad = lane >> 4, l16 = lane & 15;
  const int wr = (wave >> 1) * 64, wc = (wave & 1) * 64;

  if (zsel == 0) {
    const float osc = 0.18033688011112042f;   // log2(e)/8
    #pragma unroll
    for (int j = 0; j < 4; j++) {
      int n = col0 + wc + j * 16 + l16;
      float bb = bias[n];
      int h = n >> 6, d = n & 63;
      #pragma unroll
      for (int i = 0; i < 4; i++)
        #pragma unroll
        for (int rr = 0; rr < 4; rr++) {
          int s = row0 + wr + i * 16 + quad * 4 + rr;
          Qo[(size_t)(h * S + s) * DH + d] = f2bf((acc[i][j][rr] + bb) * osc);
        }
    }
  } else if (zsel == 1) {
    #pragma unroll
    for (int j = 0; j < 4; j++) {
      int n = col0 + wc + j * 16 + l16;
      float bb = bias[n];
      int h = n >> 6, dh = n & 63;
      int c = dh >> 4, hfk = (dh >> 3) & 1, j8 = dh & 7;
      #pragma unroll
      for (int i = 0; i < 4; i++)
        #pragma unroll
        for (int rr = 0; rr < 4; rr++) {
          int s = row0 + wr + i * 16 + quad * 4 + rr;
          int g = s >> 5, l32k = s & 31;
          K2o[((size_t)((h * 128 + g) * 4 + c) * 64 + hfk * 32 + l32k) * 8 + j8] =
              f2bf(acc[i][j][rr] + bb);
        }
    }
  } else {
    // m = key&15 = quad*4+rr -> hf_v = quad&1, j = (quad>>1)*4 + rr, grp = i&1
    #pragma unroll
    for (int j = 0; j < 4; j++) {
      int n = col0 + wc + j * 16 + l16;
      float bb = bias[n];
      int h = n >> 6, dh = n & 63;
      int ng = dh >> 5, l32v = dh & 31;
      int hf_v = quad & 1, jj0 = (quad >> 1) * 4;
      #pragma unroll
      for (int i = 0; i < 4; i++) {
        int gt = (row0 + wr + i * 16) >> 5;
        int grp = i & 1;
        ushort4 pv;
        pv.x = f2bf(acc[i][j][0] + bb); pv.y = f2bf(acc[i][j][1] + bb);
        pv.z = f2bf(acc[i][j][2] + bb); pv.w = f2bf(acc[i][j][3] + bb);
        *reinterpret_cast<ushort4*>(
            Vbo + ((size_t)(((h * 128 + gt) * 2 + grp) * 2 + ng) * 64 + hf_v * 32 + l32v) * 8 + jj0) = pv;
      }
    }
  }
}

// out = A @ W^T + bias_eff
__global__ __launch_bounds__(256) void out_gemm_kernel(
    const unsigned short* __restrict__ A, const unsigned short* __restrict__ W,
    const float* __restrict__ be, float* __restrict__ dst)
{
  __shared__ unsigned short As[128 * 32];
  __shared__ unsigned short Bs[128 * 32];
  const int row0 = blockIdx.x * 128, col0 = blockIdx.y * 128;
  f32x4 acc[4][4];
  gemm128(A, W, As, Bs, acc, row0, col0);

  const int tid = threadIdx.x;
  const int wave = tid >> 6, lane = tid & 63, quad = lane >> 4, l16 = lane & 15;
  const int wr = (wave >> 1) * 64, wc = (wave & 1) * 64;
  #pragma unroll
  for (int j = 0; j < 4; j++) {
    int n = col0 + wc + j * 16 + l16;
    float bb = be[n];
    #pragma unroll
    for (int i = 0; i < 4; i++)
      #pragma unroll
      for (int rr = 0; rr < 4; rr++) {
        int s = row0 + wr + i * 16 + quad * 4 + rr;
        dst[(size_t)s * HID + n] = acc[i][j][rr] + bb;
      }
  }
}

// VsumP[p][h*64+d] = partial sum of V over gt range (new Vb layout; perm-invariant)
__global__ __launch_bounds__(256) void vsum_kernel(
    const unsigned short* __restrict__ Vb, float* __restrict__ VsumP)
{
  __shared__ float red[256];
  const int p = blockIdx.x, h = blockIdx.y, tid = threadIdx.x;
  const int d = tid & 63, chunk = tid >> 6;
  const int ng = d >> 5, l32 = d & 31;
  float s = 0.f;
  for (int m = 0; m < 4; m++) {
    int gt = p * 16 + chunk * 4 + m;
    #pragma unroll
    for (int grp = 0; grp < 2; grp++)
      #pragma unroll
      for (int hf = 0; hf < 2; hf++) {
        uint4 u = *reinterpret_cast<const uint4*>(
            Vb + ((size_t)(((h * 128 + gt) * 2 + grp) * 2 + ng) * 64 + hf * 32 + l32) * 8);
        const unsigned int w[4] = {u.x, u.y, u.z, u.w};
        #pragma unroll
        for (int q = 0; q < 4; q++) {
          s += __builtin_bit_cast(float, w[q] << 16);
          s += __builtin_bit_cast(float, w[q] & 0xFFFF0000u);
        }
      }
  }
  red[tid] = s;
  __syncthreads();
  if (tid < 64)
    VsumP[p * 1024 + h * 64 + tid] = red[tid] + red[64 + tid] + red[128 + tid] + red[192 + tid];
}

// be[n] = bo[n] + (Vsum . wo[n,:]) / 4097, Vsum = sum of 8 partials
__global__ __launch_bounds__(256) void biasfold_kernel(
    const float* __restrict__ VsumP, const float* __restrict__ wo,
    const float* __restrict__ bo, float* __restrict__ be)
{
  const int n = blockIdx.x * 4 + (threadIdx.x >> 6);
  const int l = threadIdx.x & 63;
  float acc = 0.f;
  #pragma unroll
  for (int i = 0; i < 16; i++) {
    float vs = 0.f;
    #pragma unroll
    for (int p = 0; p < 8; p++) vs += VsumP[p * 1024 + l + 64 * i];
    acc += vs * wo[(size_t)n * HID + l + 64 * i];
  }
  #pragma unroll
  for (int off = 32; off >= 1; off >>= 1) acc += __shfl_xor(acc, off);
  if (l == 0) be[n] = bo[n] + acc * (1.f / 4097.f);
}

// ---------------------------------------------------------------- attention v11
// Collapsed double softmax (w = 1+p): out = (Vsum + softmax1(S)V)/4097.
// v11 restructure (v10 evidence: LDS unit busy ~55us/84.5us = the pole;
// MFMA throughput floor only ~7us/SIMD; 64 lockstep barriers):
//   - each wave owns ALL 64 q (Q frags x2, loop-invariant) and a 1/4 key
//     slice (32 tiles, stride 4). Every K/V tile read by exactly ONE wave
//     -> LDS b128 reads per block HALVED (2048 -> 1024).
//   - private per-wave 16KB double-buffer; NO __syncthreads in the loop.
//     Per-wave counted s_waitcnt vmcnt(8): the 8 next-tile gloads stay in
//     flight across the whole compute phase (T4), drained to 0 only at tail.
//   - MFMA:ds_read ratio doubles to 16:8 per iteration.
//   - epilogue: one barrier, 4-way cross-wave O/z reduction via the dead
//     tile LDS (Ored[4][64][64] f32 = 64KB aliases T).
// Regs ~190 -> __launch_bounds__(256,2) (cap 256, no spill).
// LDS 65KB -> 2 blocks/CU (8 waves/CU); latency hidden by explicit pipeline.
struct AttnState {
  short8 qf[2][4];
  f32x16 Oa[2][2];
  f32x16 zacc;
  f32x2  zp[2];
};

template<int BUF>
__device__ __forceinline__ void attn_compute(
    const unsigned short* kbase, const unsigned short* vbase, AttnState& st)
{
  short8 kf[4], vfr[4];
  #pragma unroll
  for (int c = 0; c < 4; c++)
    kf[c] = *reinterpret_cast<const short8*>(kbase + BUF * 4096 + c * 512);
  #pragma unroll
  for (int w = 0; w < 4; w++)
    vfr[w] = *reinterpret_cast<const short8*>(vbase + BUF * 4096 + w * 512);

  #pragma unroll
  for (int qh = 0; qh < 2; qh++) {
    // S^T tile: 32 keys x 32 q (C: col=q=l32, row=key=(reg&3)+4hf+8(reg>>2))
    f32x16 acc = __builtin_amdgcn_mfma_f32_32x32x16_bf16(kf[0], st.qf[qh][0], st.zacc, 0, 0, 0);
    #pragma unroll
    for (int c = 1; c < 4; c++)
      acc = __builtin_amdgcn_mfma_f32_32x32x16_bf16(kf[c], st.qf[qh][c], acc, 0, 0, 0);

    // exp + pack: reg-octet [0..7] / [8..15] become K=16 A-operands directly
    unsigned int D[8];
    #pragma unroll
    for (int m = 0; m < 8; m++) {
      float t0 = __builtin_amdgcn_exp2f(acc[2 * m]);
      float t1 = __builtin_amdgcn_exp2f(acc[2 * m + 1]);
      f32x2 t = {t0, t1};
      st.zp[qh] += t;                      // v_pk_add_f32
      D[m] = pktrunc(t0, t1);
    }
    u32x4 dv0 = {D[0], D[1], D[2], D[3]};
    u32x4 dv1 = {D[4], D[5], D[6], D[7]};
    short8 A0 = __builtin_bit_cast(short8, dv0);
    short8 A1 = __builtin_bit_cast(short8, dv1);

    st.Oa[qh][0] = __builtin_amdgcn_mfma_f32_32x32x16_bf16(A0, vfr[0], st.Oa[qh][0], 0, 0, 0);
    st.Oa[qh][1] = __builtin_amdgcn_mfma_f32_32x32x16_bf16(A0, vfr[1], st.Oa[qh][1], 0, 0, 0);
    st.Oa[qh][0] = __builtin_amdgcn_mfma_f32_32x32x16_bf16(A1, vfr[2], st.Oa[qh][0], 0, 0, 0);
    st.Oa[qh][1] = __builtin_amdgcn_mfma_f32_32x32x16_bf16(A1, vfr[3], st.Oa[qh][1], 0, 0, 0);
  }
}

__device__ __forceinline__ void stage_tile(
    const unsigned short* gK, const unsigned short* gV,
    unsigned short* lK, unsigned short* lV)
{
  #pragma unroll
  for (int i = 0; i < 4; i++) gload16(gK + i * 512, lK + i * 512);
  #pragma unroll
  for (int i = 0; i < 4; i++) gload16(gV + i * 512, lV + i * 512);
}

__global__ __launch_bounds__(256, 2) void attn_kernel(
    const unsigned short* __restrict__ Q, const unsigned short* __restrict__ K2,
    const unsigned short* __restrict__ Vb, unsigned short* __restrict__ OUT)
{
  __shared__ unsigned short T[4][2][2][2048];   // [wave][dbuf][K|V][2048] = 64KB
  __shared__ float Zl[256];                      // [wave][64 q]
  float* Ored = reinterpret_cast<float*>(&T[0][0][0][0]);   // [4][64][64] after loop

  // XCD-aware remap: XCD x owns heads {2x,2x+1}: K2+Vb working set 2MB (L2-fit).
  const int lin = blockIdx.y * 64 + blockIdx.x;
  const int xcd = lin & 7, idx = lin >> 3;
  const int h = xcd * 2 + (idx >> 6);
  const int q0 = (idx & 63) * 64;

  const int tid = threadIdx.x;
  const int wave = tid >> 6, lane = tid & 63, hf = lane >> 5, l32 = lane & 31;

  AttnState st;
  // Q B-frags for BOTH q-halves (loop-invariant): B[k=c*16+hf*8+j][q=l32]
  #pragma unroll
  for (int qh = 0; qh < 2; qh++) {
    const unsigned short* qrow = Q + (size_t)(h * S + q0 + qh * 32 + l32) * DH;
    #pragma unroll
    for (int c = 0; c < 4; c++)
      st.qf[qh][c] = *reinterpret_cast<const short8*>(qrow + c * 16 + hf * 8);
  }
  #pragma unroll
  for (int r = 0; r < 16; r++) {
    st.zacc[r] = 0.f;
    st.Oa[0][0][r] = 0.f; st.Oa[0][1][r] = 0.f;
    st.Oa[1][0][r] = 0.f; st.Oa[1][1][r] = 0.f;
  }
  st.zp[0] = (f32x2){0.f, 0.f};
  st.zp[1] = (f32x2){0.f, 0.f};

  const unsigned short* Kb  = K2 + (size_t)h * 128 * 2048;
  const unsigned short* Vbb = Vb + (size_t)h * 128 * 2048;

  // wave handles tiles g = wave + 4*i, i = 0..31 (each tile = 32 keys, 4KB K + 4KB V)
  const unsigned short* gK = Kb  + (size_t)wave * 2048 + (size_t)lane * 8;
  const unsigned short* gV = Vbb + (size_t)wave * 2048 + (size_t)lane * 8;
  unsigned short* lK0 = &T[wave][0][0][0];   // wave-uniform LDS dests
  unsigned short* lV0 = &T[wave][0][1][0];
  unsigned short* lK1 = &T[wave][1][0][0];
  unsigned short* lV1 = &T[wave][1][1][0];
  const unsigned short* kbase = &T[wave][0][0][0] + lane * 8;
  const unsigned short* vbase = &T[wave][0][1][0] + lane * 8;
  const ptrdiff_t STR = 4 * 2048;   // 4 tiles ahead (wave stride)

  // prologue: stage tile i=0 into buf 0
  stage_tile(gK, gV, lK0, lV0); gK += STR; gV += STR;

  // 15 pairs: compute tile 2t (buf0) while staging 2t+1 (buf1), then swap.
  // vmcnt(8) = only the 8 just-issued loads may remain in flight ->
  // the current buffer's loads (issued last iteration) have landed.
  for (int t = 0; t < 15; t++) {
    stage_tile(gK, gV, lK1, lV1); gK += STR; gV += STR;
    VMCNT8;
    attn_compute<0>(kbase, vbase, st);
    stage_tile(gK, gV, lK0, lV0); gK += STR; gV += STR;
    VMCNT8;
    attn_compute<1>(kbase, vbase, st);
  }
  // tail: tiles 30, 31
  stage_tile(gK, gV, lK1, lV1);
  VMCNT8;
  attn_compute<0>(kbase, vbase, st);
  VMCNT0;
  attn_compute<1>(kbase, vbase, st);

  // ---- epilogue: cross-wave reduction through the dead tile LDS ----
  __syncthreads();   // everyone done streaming; T reusable as Ored
  {
    float za = st.zp[0][0] + st.zp[0][1];
    float zb = st.zp[1][0] + st.zp[1][1];
    za += __shfl_xor(za, 32);
    zb += __shfl_xor(zb, 32);
    if (hf == 0) {
      Zl[wave * 64 + l32]      = za;
      Zl[wave * 64 + 32 + l32] = zb;
    }
    float* Ow = Ored + wave * 4096;   // [64 q][64 d]
    #pragma unroll
    for (int qh = 0; qh < 2; qh++)
      #pragma unroll
      for (int ng = 0; ng < 2; ng++)
        #pragma unroll
        for (int r = 0; r < 16; r++) {
          const int row = (r & 3) + 8 * (r >> 2) + 4 * hf;
          Ow[(qh * 32 + row) * 64 + ng * 32 + l32] = st.Oa[qh][ng][r];
        }
  }
  __syncthreads();
  {
    const int q = tid >> 2, d0 = (tid & 3) * 16;
    const float* O0 = Ored + q * 64 + d0;
    f32x4 s0 = *reinterpret_cast<const f32x4*>(O0);
    f32x4 s1 = *reinterpret_cast<const f32x4*>(O0 + 4);
    f32x4 s2 = *reinterpret_cast<const f32x4*>(O0 + 8);
    f32x4 s3 = *reinterpret_cast<const f32x4*>(O0 + 12);
    #pragma unroll
    for (int w = 1; w < 4; w++) {
      const float* Ow = Ored + w * 4096 + q * 64 + d0;
      s0 += *reinterpret_cast<const f32x4*>(Ow);
      s1 += *reinterpret_cast<const f32x4*>(Ow + 4);
      s2 += *reinterpret_cast<const f32x4*>(Ow + 8);
      s3 += *reinterpret_cast<const f32x4*>(Ow + 12);
    }
    const float zt = Zl[q] + Zl[64 + q] + Zl[128 + q] + Zl[192 + q];
    const float rz = 1.f / (zt * 4097.f);
    unsigned short* op = OUT + (size_t)(q0 + q) * HID + h * DH + d0;
    ushort4 u;
    u.x = f2bf(s0[0] * rz); u.y = f2bf(s0[1] * rz);
    u.z = f2bf(s0[2] * rz); u.w = f2bf(s0[3] * rz);
    *reinterpret_cast<ushort4*>(op) = u;
    u.x = f2bf(s1[0] * rz); u.y = f2bf(s1[1] * rz);
    u.z = f2bf(s1[2] * rz); u.w = f2bf(s1[3] * rz);
    *reinterpret_cast<ushort4*>(op + 4) = u;
    u.x = f2bf(s2[0] * rz); u.y = f2bf(s2[1] * rz);
    u.z = f2bf(s2[2] * rz); u.w = f2bf(s2[3] * rz);
    *reinterpret_cast<ushort4*>(op + 8) = u;
    u.x = f2bf(s3[0] * rz); u.y = f2bf(s3[1] * rz);
    u.z = f2bf(s3[2] * rz); u.w = f2bf(s3[3] * rz);
    *reinterpret_cast<ushort4*>(op + 12) = u;
  }
}

// ----------------------------------------------------------------
extern "C" void kernel_launch(void* const* d_in, const int* in_sizes, int n_in,
                              void* d_out, int out_size, void* d_ws, size_t ws_size,
                              hipStream_t stream) {
  const float* x  = (const float*)d_in[0];
  const float* wq = (const float*)d_in[1];
  const float* bq = (const float*)d_in[2];
  const float* wk = (const float*)d_in[3];
  const float* bk = (const float*)d_in[4];
  const float* wv = (const float*)d_in[5];
  const float* bv = (const float*)d_in[6];
  const float* wo = (const float*)d_in[7];
  const float* bo = (const float*)d_in[8];
  float* out = (float*)d_out;

  char* ws = (char*)d_ws;
  unsigned short* xb  = (unsigned short*)(ws);                 // 8 MB (reused for attn out)
  unsigned short* wqb = (unsigned short*)(ws + (8u  << 20));
  unsigned short* wkb = (unsigned short*)(ws + (10u << 20));
  unsigned short* wvb = (unsigned short*)(ws + (12u << 20));
  unsigned short* wob = (unsigned short*)(ws + (14u << 20));
  unsigned short* qw  = (unsigned short*)(ws + (16u << 20));   // [H][S][64] prescaled
  unsigned short* k2  = (unsigned short*)(ws + (24u << 20));   // frag-packed K (K=16 A-op)
  unsigned short* vb  = (unsigned short*)(ws + (32u << 20));   // frag-packed V (K=16 B-op, relabeled)
  float* vsump        = (float*)(ws + (40u << 20));            // [8][1024]
  float* be           = (float*)(ws + (40u << 20) + 65536);    // [1024]
  unsigned short* aw  = xb;

  cast_kernel<<<dim3(4096, 5), 256, 0, stream>>>(x, wq, wk, wv, wo, xb, wqb, wkb, wvb, wob);
  qkv_gemm_kernel<<<dim3(32, 8, 3), 256, 0, stream>>>(xb, wqb, wkb, wvb, bq, bk, bv, qw, k2, vb);
  vsum_kernel<<<dim3(8, 16), 256, 0, stream>>>(vb, vsump);
  biasfold_kernel<<<dim3(256), 256, 0, stream>>>(vsump, wo, bo, be);
  attn_kernel<<<dim3(64, 16), 256, 0, stream>>>(qw, k2, vb, aw);
  out_gemm_kernel<<<dim3(32, 8, 1), 256, 0, stream>>>(aw, wob, be, out);
}